// Round 14
// baseline (101.831 us; speedup 1.0000x reference)
//
#include <hip/hip_runtime.h>

#define TT 200
#define FF 32
#define HH 50

typedef _Float16 half8 __attribute__((ext_vector_type(8)));   // 8 f16 = 4 VGPR
typedef __attribute__((ext_vector_type(4))) float f32x4;
typedef __attribute__((ext_vector_type(4))) unsigned int uint32x4;

// tanh(x) = 1 - 2/(exp2(2*log2e*x)+1)
__device__ __forceinline__ float fast_tanh(float x) {
    float e = exp2f(2.885390082f * x);
    return fmaf(-2.0f, __builtin_amdgcn_rcpf(e + 1.0f), 1.0f);
}
__device__ __forceinline__ f32x4 mfmah(half8 a, half8 b, f32x4 c) {
    return __builtin_amdgcn_mfma_f32_16x16x32_f16(a, b, c, 0, 0, 0);
}

// fp16 B-frag of M[kdim x 50] col-slice (RNE). Layout (validated r4-r13):
// lane(r,g) elem e -> B[k=kbase+8g+e][col=c].
__device__ __forceinline__ half8 build_wfrag(const float* __restrict__ M, int kbase,
                                             int kmax, int c, bool cv, int g) {
    unsigned u[4];
#pragma unroll
    for (int q = 0; q < 4; ++q) {
        const int k0 = kbase + 8 * g + 2 * q, k1 = k0 + 1;
        _Float16 v0 = (_Float16)((cv && k0 < kmax) ? M[k0 * HH + c] : 0.0f);
        _Float16 v1 = (_Float16)((cv && k1 < kmax) ? M[k1 * HH + c] : 0.0f);
        u[q] = ((unsigned)__builtin_bit_cast(unsigned short, v1) << 16)
             |  __builtin_bit_cast(unsigned short, v0);
    }
    uint32x4 uu = {u[0], u[1], u[2], u[3]};
    return __builtin_bit_cast(half8, uu);
}

// 8 f32 -> half8 via v_cvt_pkrtz (x path only)
__device__ __forceinline__ half8 cvt8(float4 a, float4 b) {
    unsigned u0 = __builtin_bit_cast(unsigned, __builtin_amdgcn_cvt_pkrtz(a.x, a.y));
    unsigned u1 = __builtin_bit_cast(unsigned, __builtin_amdgcn_cvt_pkrtz(a.z, a.w));
    unsigned u2 = __builtin_bit_cast(unsigned, __builtin_amdgcn_cvt_pkrtz(b.x, b.y));
    unsigned u3 = __builtin_bit_cast(unsigned, __builtin_amdgcn_cvt_pkrtz(b.z, b.w));
    uint32x4 uu = {u0, u1, u2, u3};
    return __builtin_bit_cast(half8, uu);
}

// r13 structure (1 wave/block, 2 real rows M-dup x8, 2048 blocks = 2
// phase-independent waves/SIMD) with ZERO LDS on the recurrence path:
//  - h round-trip replaced by ds_bpermute full-wave crossbar (LDS pipe,
//    no memory): lane c holds pk=(h0[c],h1[c]) packed f16x2; 16
//    loop-invariant indices pull k=8g+e words; 8 v_perm (loop-invariant
//    rl-selector) assemble the two A-frags. Kills ds_write+drain+ds_read
//    (~250 cyc) from the 200x serial path.
//  - serial 2-MFMA chains (r13 post-mortem: parallel chains + f32x4 adds
//    forced ~32 v_accvgpr_read + 16 v_add per step; serial keeps C in the
//    MFMA domain; only 8 selected elements are read out).
__global__
__attribute__((amdgpu_flat_work_group_size(64, 64)))
__attribute__((amdgpu_waves_per_eu(2, 2)))
void rnn_fp16(const float* __restrict__ x, const float* __restrict__ W,
              const float* __restrict__ U, const float* __restrict__ b,
              const float* __restrict__ Wd, const float* __restrict__ bd,
              float* __restrict__ out)
{
    const int l  = threadIdx.x & 63;
    const int r  = l & 15;
    const int g  = l >> 4;
    const int rl = r & 1;          // real row (M rows duplicated x8)
    const int rb = blockIdx.x * 2;
    const bool gs1 = (g & 1) != 0, gs2 = (g & 2) != 0;

    // weight frags (48 VGPR) + persistent bias C-source (16 VGPR)
    half8 Wf[4], U0[4], U1[4];
    f32x4 biasv[4];
#pragma unroll
    for (int n = 0; n < 4; ++n) {
        const int c = 16 * n + r;
        const bool cv = (c < HH);
        Wf[n] = build_wfrag(W, 0,  FF, c, cv, g);
        U0[n] = build_wfrag(U, 0,  HH, c, cv, g);
        U1[n] = build_wfrag(U, 32, HH, c, cv, g);
        const float bv = cv ? b[c] : 0.0f;
        biasv[n] = (f32x4){bv, bv, bv, bv};
    }
    const int cg = 16 * g + r;                      // this lane's h column
    const float wd = (cg < HH) ? Wd[cg] : 0.0f;

    // loop-invariant bpermute byte-indices and v_perm row-selector
    int idxA[8], idxB[8];
#pragma unroll
    for (int e = 0; e < 8; ++e) {
        idxA[e] = (8 * g + e) * 4;          // k = 0..31  -> source lane k
        idxB[e] = (32 + 8 * g + e) * 4;     // k = 32..63 -> source lane k
    }
    const unsigned psel = rl ? 0x07060302u : 0x05040100u;   // hi16 : lo16

    const float* xrow = x + (size_t)(rb + rl) * TT * FF + 8 * g;

    // nx[n] = biasv + x_t @ W (1 MFMA/tile, persistent biasv C)
    auto do_nx = [&](float4 a, float4 b2, f32x4 (&nx)[4]) {
        half8 xa = cvt8(a, b2);
#pragma unroll
        for (int n = 0; n < 4; ++n) nx[n] = mfmah(xa, Wf[n], biasv[n]);
    };

    // prologue: xc = x_0@W; prefetch x_1 (pa), x_2 (pb)
    f32x4 xc[4], xn[4];
    do_nx(*(const float4*)(xrow), *(const float4*)(xrow + 4), xc);
    float4 pa0 = *(const float4*)(xrow + FF),     pa1 = *(const float4*)(xrow + FF + 4);
    float4 pb0 = *(const float4*)(xrow + 2 * FF), pb1 = *(const float4*)(xrow + 2 * FF + 4);

    unsigned pk = 0;                // packed (h_t[cg] row0, row1) — loop carried
    float hf0 = 0.0f, hf1 = 0.0f;   // this lane's final h for the head

    auto step = [&](int t, bool first,
                    f32x4 (&xcur)[4], f32x4 (&xnext)[4], float4& qa, float4& qb) {
        // in-register transpose of h_t: bpermute pulls + perm row-select
        half8 A0, A1;
        if (!first) {
            unsigned wA[8], wB[8];
#pragma unroll
            for (int e = 0; e < 8; ++e)
                wA[e] = (unsigned)__builtin_amdgcn_ds_bpermute(idxA[e], (int)pk);
#pragma unroll
            for (int e = 0; e < 8; ++e)
                wB[e] = (unsigned)__builtin_amdgcn_ds_bpermute(idxB[e], (int)pk);
            uint32x4 a0 = {__builtin_amdgcn_perm(wA[1], wA[0], psel),
                           __builtin_amdgcn_perm(wA[3], wA[2], psel),
                           __builtin_amdgcn_perm(wA[5], wA[4], psel),
                           __builtin_amdgcn_perm(wA[7], wA[6], psel)};
            uint32x4 a1 = {__builtin_amdgcn_perm(wB[1], wB[0], psel),
                           __builtin_amdgcn_perm(wB[3], wB[2], psel),
                           __builtin_amdgcn_perm(wB[5], wB[4], psel),
                           __builtin_amdgcn_perm(wB[7], wB[6], psel)};
            A0 = __builtin_bit_cast(half8, a0);
            A1 = __builtin_bit_cast(half8, a1);
        }
        // x_{t+1}@W (independent of h) + advance prefetch to x_{t+3}
        do_nx(qa, qb, xnext);
        int tn = t + 3; if (tn > TT - 1) tn = TT - 1;
        qa = *(const float4*)(xrow + (size_t)tn * FF);
        qb = *(const float4*)(xrow + (size_t)tn * FF + 4);

        f32x4 tot[4];
        if (!first) {
#pragma unroll
            for (int n = 0; n < 4; ++n)    // serial 2-chain: C stays in MFMA domain
                tot[n] = mfmah(A1, U1[n], mfmah(A0, U0[n], xcur[n]));
        } else {
#pragma unroll
            for (int n = 0; n < 4; ++n) tot[n] = xcur[n];
        }

        // M-dup select (lane owns tile g), tanh, repack for next transpose
        float a0 = gs1 ? tot[1][0] : tot[0][0];
        float a1 = gs1 ? tot[1][1] : tot[0][1];
        float c0 = gs1 ? tot[3][0] : tot[2][0];
        float c1 = gs1 ? tot[3][1] : tot[2][1];
        float m0 = gs2 ? c0 : a0;
        float m1 = gs2 ? c1 : a1;
        hf0 = fast_tanh(m0);
        hf1 = fast_tanh(m1);
        pk = __builtin_bit_cast(unsigned, __builtin_amdgcn_cvt_pkrtz(hf0, hf1));
        // no LDS, no barrier, no waitcnt on the recurrence path
    };

    step(0, true, xc, xn, pa0, pa1);
    for (int t = 1; t < TT - 1; t += 2) {
        step(t,     false, xn, xc, pb0, pb1);
        step(t + 1, false, xc, xn, pa0, pa1);
    }
    step(TT - 1, false, xn, xc, pb0, pb1);

    // head: out[row i] = relu(sum_c h[i][c]*Wd[c] + bd)
    float p0 = hf0 * wd, p1 = hf1 * wd;
#pragma unroll
    for (int m = 1; m <= 32; m <<= 1) {
        p0 += __shfl_xor(p0, m);
        p1 += __shfl_xor(p1, m);
    }
    if (l == 0) {
        const float bdv = bd[0];
        out[rb + 0] = fmaxf(p0 + bdv, 0.0f);
        out[rb + 1] = fmaxf(p1 + bdv, 0.0f);
    }
}

extern "C" void kernel_launch(void* const* d_in, const int* in_sizes, int n_in,
                              void* d_out, int out_size, void* d_ws, size_t ws_size,
                              hipStream_t stream) {
    const float* x  = (const float*)d_in[0];
    const float* W  = (const float*)d_in[1];
    const float* U  = (const float*)d_in[2];
    const float* b  = (const float*)d_in[3];
    const float* Wd = (const float*)d_in[4];
    const float* bd = (const float*)d_in[5];
    float* out = (float*)d_out;
    const int B = out_size;                       // 4096
    dim3 grid(B / 2), block(64);                  // 2048 blocks, 1 wave, 2 rows
    hipLaunchKernelGGL(rnn_fp16, grid, block, 0, stream,
                       x, W, U, b, Wd, bd, out);
    (void)d_ws; (void)ws_size; (void)in_sizes; (void)n_in;
}